// Round 7
// baseline (1720.331 us; speedup 1.0000x reference)
//
#include <hip/hip_runtime.h>
#include <hip/hip_fp16.h>

#define EPS 1e-5f
#define ABITS 8           // 256 nodes per dst-bucket
#define NBKT_MAX 512      // allocated bucket-meta slots (>= 391)
#define ACHUNK 2048       // edges per block in bucket pass A
#define BCAP 4096         // edge capacity per bucket (avg ~3072, ~18 sigma margin)
#define CSHIFT 13         // src-chunk = src >> 13 (1 MB of t per chunk)
#define APAD 65           // acc row stride in floats: bank = (d + 8*fl + j) % 32 -> ~2-way
// edge packing: (dstOff << 17) | src  — requires N <= 131072 (N=100000 ok)

typedef _Float16 half8 __attribute__((ext_vector_type(8)));
typedef float floatx4 __attribute__((ext_vector_type(4)));

// ---------------- prep A: bucket edges by dst (unchanged structure) ----------------

__global__ __launch_bounds__(256) void bucketA_kernel(const int* __restrict__ ei, int E,
                                                      int* __restrict__ bucket_fill, unsigned* __restrict__ tmp) {
    __shared__ int2 edg[ACHUNK];            // 16 KB
    __shared__ int hist[NBKT_MAX], lbase[NBKT_MAX], lcur[NBKT_MAX];   // 6 KB
    int t = threadIdx.x;
    for (int i = t; i < NBKT_MAX; i += 256) { hist[i] = 0; lcur[i] = 0; }
    __syncthreads();
    int e0 = blockIdx.x * ACHUNK;
    int e1 = e0 + ACHUNK; if (e1 > E) e1 = E;
    int ne = e1 - e0;
    for (int idx = t; idx < ne; idx += 256) {
        int r = ei[e0 + idx], c = ei[E + e0 + idx];
        edg[idx] = make_int2(r, c);
        atomicAdd(&hist[c >> ABITS], 1);
    }
    __syncthreads();
    for (int i = t; i < NBKT_MAX; i += 256) {
        int h = hist[i];
        if (h) lbase[i] = atomicAdd(&bucket_fill[i], h);
    }
    __syncthreads();
    for (int idx = t; idx < ne; idx += 256) {
        int2 e = edg[idx];
        int b = e.y >> ABITS;
        int l = atomicAdd(&lcur[b], 1);
        tmp[(size_t)b * BCAP + lbase[b] + l] = ((unsigned)(e.y & 255) << 17) | (unsigned)e.x;
    }
}

// ---------------- prep B: per bucket — deg/dinv + 32-bin (half,chunk) counting sort ----------------
// Output eb[bucket]: edges ordered by (dst-half, src-chunk); hb[bucket] = half-0 count.
// No padding, no per-node csr, no perm — push-model agg consumes edges directly.

__global__ __launch_bounds__(256) void bucketB_kernel(const unsigned* __restrict__ tmp,
                                                      const int* __restrict__ bucket_fill,
                                                      float* __restrict__ dinv,
                                                      unsigned* __restrict__ eb, int* __restrict__ hb, int n) {
    __shared__ unsigned edg[BCAP];          // 16 KB
    __shared__ int deg[256];
    __shared__ int cnt[32], cur[32];
    int b = blockIdx.x, t = threadIdx.x;
    int n0 = b << ABITS;
    int cntN = n - n0; if (cntN > 256) cntN = 256;
    int ne = bucket_fill[b]; if (ne > BCAP) ne = BCAP;
    size_t base = (size_t)b * BCAP;
    deg[t] = 0;
    if (t < 32) cnt[t] = 0;
    for (int i = t; i < ne; i += 256) edg[i] = tmp[base + i];
    __syncthreads();
    for (int i = t; i < ne; i += 256) {
        unsigned e = edg[i];
        int d = e >> 17, src = e & 0x1FFFF;
        atomicAdd(&deg[d], 1);
        atomicAdd(&cnt[((d >> 7) << 4) | (src >> CSHIFT)], 1);
    }
    __syncthreads();
    if (t == 0) {
        int run = 0;
        for (int c = 0; c < 32; ++c) { cur[c] = run; run += cnt[c]; }
        hb[b] = cur[16];                    // boundary between half 0 and half 1
    }
    __syncthreads();
    if (t < cntN) dinv[n0 + t] = rsqrtf((float)(deg[t] + 1));
    for (int i = t; i < ne; i += 256) {
        unsigned e = edg[i];
        int d = e >> 17, src = e & 0x1FFFF;
        int pos = atomicAdd(&cur[((d >> 7) << 4) | (src >> CSHIFT)], 1);
        eb[base + pos] = e;
    }
}

// ---------------- layer-0 dense GEMM via MFMA: [n,128]@[128,64] -> dinv*h (fp16) ----------------

template <int K, typename TIN>
__global__ __launch_bounds__(256) void gemm_kernel(const TIN* __restrict__ A, const float* __restrict__ W,
                                                   const float* __restrict__ dinv, __half* __restrict__ out, int n) {
    const int KP = K + 8;
    __shared__ _Float16 Ah[64 * (K + 8)];
    __shared__ _Float16 Wt[64 * (K + 8)];
    int tid = threadIdx.x;

    for (int idx = tid; idx < K * 64; idx += 256) {
        int k = idx >> 6, c = idx & 63;
        Wt[c * KP + k] = (_Float16)W[idx];
    }
    int row0 = blockIdx.x * 64;
    const TIN* Ab = A + (size_t)row0 * K;
    int limit = (n - row0) * K; if (limit > 64 * K) limit = 64 * K;

    for (int f = tid * 4; f < 64 * K; f += 1024) {
        float4 v = make_float4(0.f, 0.f, 0.f, 0.f);
        if (f + 3 < limit) {
            v = *(const float4*)((const float*)Ab + f);
        } else {
            if (f + 0 < limit) v.x = ((const float*)Ab)[f + 0];
            if (f + 1 < limit) v.y = ((const float*)Ab)[f + 1];
            if (f + 2 < limit) v.z = ((const float*)Ab)[f + 2];
        }
        int row = f / K, k = f % K;
        _Float16* dst = Ah + row * KP + k;
        dst[0] = (_Float16)v.x; dst[1] = (_Float16)v.y;
        dst[2] = (_Float16)v.z; dst[3] = (_Float16)v.w;
    }
    __syncthreads();

    int w = tid >> 6, lane = tid & 63;
    int m = lane & 15, quad = lane >> 4;
    const _Float16* Aw = Ah + (size_t)(w * 16 + m) * KP + quad * 8;
    const _Float16* Bw = Wt + (size_t)m * KP + quad * 8;

    floatx4 acc0 = {0.f, 0.f, 0.f, 0.f}, acc1 = acc0, acc2 = acc0, acc3 = acc0;
    for (int k0 = 0; k0 < K; k0 += 32) {
        half8 a  = *(const half8*)(Aw + k0);
        half8 b0 = *(const half8*)(Bw + 0 * 16 * KP + k0);
        half8 b1 = *(const half8*)(Bw + 1 * 16 * KP + k0);
        half8 b2 = *(const half8*)(Bw + 2 * 16 * KP + k0);
        half8 b3 = *(const half8*)(Bw + 3 * 16 * KP + k0);
        acc0 = __builtin_amdgcn_mfma_f32_16x16x32_f16(a, b0, acc0, 0, 0, 0);
        acc1 = __builtin_amdgcn_mfma_f32_16x16x32_f16(a, b1, acc1, 0, 0, 0);
        acc2 = __builtin_amdgcn_mfma_f32_16x16x32_f16(a, b2, acc2, 0, 0, 0);
        acc3 = __builtin_amdgcn_mfma_f32_16x16x32_f16(a, b3, acc3, 0, 0, 0);
    }

    int rbase = row0 + w * 16 + quad * 4;
#pragma unroll
    for (int r = 0; r < 4; ++r) {
        int row = rbase + r;
        if (row < n) {
            float dv = dinv[row];
            __half* o = out + (size_t)row * 64 + m;
            o[0]  = __float2half(acc0[r] * dv);
            o[16] = __float2half(acc1[r] * dv);
            o[32] = __float2half(acc2[r] * dv);
            o[48] = __float2half(acc3[r] * dv);
        }
    }
}

// ---------------- push-model aggregation + BN/ReLU (+GEMM or classifier) ----------------
// One block per 256-node dst bucket, processed as two 128-node halves with fp32
// LDS accumulators [128][APAD]. Edges chunk-sorted -> all 391 resident blocks walk
// the same 1 MB src windows in order (cross-block L2 reuse). 8-lane group per edge:
// one 128 B row read + 8 ds_add_f32. Epilogue: self-add + dinv + BN/ReLU, then
// 128x64 @ 64x64 MFMA and coalesced consecutive-row writes.

__device__ __forceinline__ void bn_relu_node(const float* __restrict__ a, const __half* __restrict__ t,
                                             int node, int fl,
                                             const float* __restrict__ dinv,
                                             const float* __restrict__ bias, const float* __restrict__ gamma,
                                             const float* __restrict__ beta, const float* __restrict__ mean,
                                             const float* __restrict__ var,
                                             float4& resL, float4& resH) {
    uint4 self = *(const uint4*)(t + (size_t)node * 64 + fl * 8);
    float2 p0 = __half22float2(*(const __half2*)&self.x);
    float2 p1 = __half22float2(*(const __half2*)&self.y);
    float2 p2 = __half22float2(*(const __half2*)&self.z);
    float2 p3 = __half22float2(*(const __half2*)&self.w);
    float di = dinv[node];
    float4 lo, hi;
    lo.x = (a[0] + p0.x) * di; lo.y = (a[1] + p0.y) * di;
    lo.z = (a[2] + p1.x) * di; lo.w = (a[3] + p1.y) * di;
    hi.x = (a[4] + p2.x) * di; hi.y = (a[5] + p2.y) * di;
    hi.z = (a[6] + p3.x) * di; hi.w = (a[7] + p3.y) * di;
    float4 bbL = ((const float4*)bias)[2 * fl],  bbH = ((const float4*)bias)[2 * fl + 1];
    float4 ggL = ((const float4*)gamma)[2 * fl], ggH = ((const float4*)gamma)[2 * fl + 1];
    float4 beL = ((const float4*)beta)[2 * fl],  beH = ((const float4*)beta)[2 * fl + 1];
    float4 mmL = ((const float4*)mean)[2 * fl],  mmH = ((const float4*)mean)[2 * fl + 1];
    float4 vvL = ((const float4*)var)[2 * fl],   vvH = ((const float4*)var)[2 * fl + 1];
    resL.x = fmaxf((lo.x + bbL.x - mmL.x) * (ggL.x * rsqrtf(vvL.x + EPS)) + beL.x, 0.f);
    resL.y = fmaxf((lo.y + bbL.y - mmL.y) * (ggL.y * rsqrtf(vvL.y + EPS)) + beL.y, 0.f);
    resL.z = fmaxf((lo.z + bbL.z - mmL.z) * (ggL.z * rsqrtf(vvL.z + EPS)) + beL.z, 0.f);
    resL.w = fmaxf((lo.w + bbL.w - mmL.w) * (ggL.w * rsqrtf(vvL.w + EPS)) + beL.w, 0.f);
    resH.x = fmaxf((hi.x + bbH.x - mmH.x) * (ggH.x * rsqrtf(vvH.x + EPS)) + beH.x, 0.f);
    resH.y = fmaxf((hi.y + bbH.y - mmH.y) * (ggH.y * rsqrtf(vvH.y + EPS)) + beH.y, 0.f);
    resH.z = fmaxf((hi.z + bbH.z - mmH.z) * (ggH.z * rsqrtf(vvH.z + EPS)) + beH.z, 0.f);
    resH.w = fmaxf((hi.w + bbH.w - mmH.w) * (ggH.w * rsqrtf(vvH.w + EPS)) + beH.w, 0.f);
}

template <bool CLS>
__global__ __launch_bounds__(256, 3) void agg_push_kernel(
        const __half* __restrict__ t, const float* __restrict__ dinv,
        const unsigned* __restrict__ eb, const int* __restrict__ bucket_fill,
        const int* __restrict__ hb,
        const float* __restrict__ bias, const float* __restrict__ gamma,
        const float* __restrict__ beta, const float* __restrict__ mean,
        const float* __restrict__ var,
        const float* __restrict__ W,          // [64][64] row-major (layers 0/1)
        const float* __restrict__ cls_w, const float* __restrict__ cls_b,
        __half* __restrict__ tout, float* __restrict__ fout, int n) {
    __shared__ float acc[128 * APAD];         // 33.3 KB (then reused as fp16 A-tile)
    __shared__ _Float16 Wt[64 * 72];          // 9 KB
    int tid = threadIdx.x;
    int b = blockIdx.x;
    int n0 = b << ABITS;
    int ntot = n - n0; if (ntot > 256) ntot = 256;
    int ne = bucket_fill[b]; if (ne > BCAP) ne = BCAP;
    int ne0 = hb[b];
    size_t base = (size_t)b * BCAP;

    if (!CLS) {
        for (int idx = tid; idx < 64 * 64; idx += 256) {
            int k = idx >> 6, c = idx & 63;
            Wt[c * 72 + k] = (_Float16)W[idx];
        }
    }

    int g = tid >> 3, fl = tid & 7;           // 32 groups x 8 lanes
    int wv = tid >> 6, lane = tid & 63;
    int m = lane & 15, quad = lane >> 4;

    for (int half = 0; half < 2; ++half) {
        int h0 = n0 + (half ? 128 : 0);
        int cntH = ntot - (half ? 128 : 0);
        if (cntH > 128) cntH = 128; if (cntH < 0) cntH = 0;
        int es = half ? ne0 : 0;
        int ee = half ? ne : ne0;

        for (int i = tid; i < 128 * APAD; i += 256) acc[i] = 0.f;
        __syncthreads();

        // edge-parallel push: 1 edge per 8-lane group per iteration
        for (int e = es + g; e < ee; e += 32) {
            unsigned p = eb[base + e];
            int d = (p >> 17) & 127, s = p & 0x1FFFF;
            uint4 r = *(const uint4*)(t + (size_t)s * 64 + fl * 8);
            float* a = acc + d * APAD + fl * 8;
            float2 q0 = __half22float2(*(const __half2*)&r.x);
            float2 q1 = __half22float2(*(const __half2*)&r.y);
            float2 q2 = __half22float2(*(const __half2*)&r.z);
            float2 q3 = __half22float2(*(const __half2*)&r.w);
            atomicAdd(a + 0, q0.x); atomicAdd(a + 1, q0.y);
            atomicAdd(a + 2, q1.x); atomicAdd(a + 3, q1.y);
            atomicAdd(a + 4, q2.x); atomicAdd(a + 5, q2.y);
            atomicAdd(a + 6, q3.x); atomicAdd(a + 7, q3.y);
        }
        __syncthreads();

        if (!CLS) {
            // BN/ReLU into registers (4 nodes per group), then stage fp16 A-tile over acc
            uint4 pk[4];
#pragma unroll
            for (int it = 0; it < 4; ++it) {
                int d = g + it * 32;
                uint4 v = make_uint4(0, 0, 0, 0);
                if (d < cntH) {
                    float4 resL, resH;
                    bn_relu_node(acc + d * APAD + fl * 8, t, h0 + d, fl, dinv,
                                 bias, gamma, beta, mean, var, resL, resH);
                    __half2 h0p = __floats2half2_rn(resL.x, resL.y);
                    __half2 h1p = __floats2half2_rn(resL.z, resL.w);
                    __half2 h2p = __floats2half2_rn(resH.x, resH.y);
                    __half2 h3p = __floats2half2_rn(resH.z, resH.w);
                    v.x = *(unsigned*)&h0p; v.y = *(unsigned*)&h1p;
                    v.z = *(unsigned*)&h2p; v.w = *(unsigned*)&h3p;
                }
                pk[it] = v;
            }
            __syncthreads();
            _Float16* A = (_Float16*)acc;     // [128][72] fp16
#pragma unroll
            for (int it = 0; it < 4; ++it) {
                int d = g + it * 32;
                *(uint4*)(A + d * 72 + fl * 8) = pk[it];
            }
            __syncthreads();
            // MFMA: wave wv covers row-tiles 2wv, 2wv+1; all 64 cols
#pragma unroll
            for (int rt = 0; rt < 2; ++rt) {
                int r0 = (wv * 2 + rt) * 16;
                const _Float16* Aw = A + (r0 + m) * 72 + quad * 8;
                floatx4 o0 = {0.f, 0.f, 0.f, 0.f}, o1 = o0, o2 = o0, o3 = o0;
#pragma unroll
                for (int k0 = 0; k0 < 64; k0 += 32) {
                    half8 av = *(const half8*)(Aw + k0);
                    half8 b0 = *(const half8*)(Wt + ( 0 + m) * 72 + quad * 8 + k0);
                    half8 b1 = *(const half8*)(Wt + (16 + m) * 72 + quad * 8 + k0);
                    half8 b2 = *(const half8*)(Wt + (32 + m) * 72 + quad * 8 + k0);
                    half8 b3 = *(const half8*)(Wt + (48 + m) * 72 + quad * 8 + k0);
                    o0 = __builtin_amdgcn_mfma_f32_16x16x32_f16(av, b0, o0, 0, 0, 0);
                    o1 = __builtin_amdgcn_mfma_f32_16x16x32_f16(av, b1, o1, 0, 0, 0);
                    o2 = __builtin_amdgcn_mfma_f32_16x16x32_f16(av, b2, o2, 0, 0, 0);
                    o3 = __builtin_amdgcn_mfma_f32_16x16x32_f16(av, b3, o3, 0, 0, 0);
                }
#pragma unroll
                for (int r = 0; r < 4; ++r) {
                    int row = r0 + quad * 4 + r;
                    if (row < cntH) {
                        int node = h0 + row;
                        float dv = dinv[node];
                        __half* o = tout + (size_t)node * 64 + m;
                        o[0]  = __float2half(o0[r] * dv);
                        o[16] = __float2half(o1[r] * dv);
                        o[32] = __float2half(o2[r] * dv);
                        o[48] = __float2half(o3[r] * dv);
                    }
                }
            }
            __syncthreads();   // before next half zeroes acc
        } else {
            for (int d = g; d < cntH; d += 32) {
                int node = h0 + d;
                float4 resL, resH;
                bn_relu_node(acc + d * APAD + fl * 8, t, node, fl, dinv,
                             bias, gamma, beta, mean, var, resL, resH);
                const float4* cw = (const float4*)cls_w;
                float4 cwA = cw[4 * fl + 0], cwB = cw[4 * fl + 1], cwC = cw[4 * fl + 2], cwD = cw[4 * fl + 3];
                float c0 = resL.x * cwA.x + resL.y * cwA.z + resL.z * cwB.x + resL.w * cwB.z
                         + resH.x * cwC.x + resH.y * cwC.z + resH.z * cwD.x + resH.w * cwD.z;
                float c1 = resL.x * cwA.y + resL.y * cwA.w + resL.z * cwB.y + resL.w * cwB.w
                         + resH.x * cwC.y + resH.y * cwC.w + resH.z * cwD.y + resH.w * cwD.w;
                for (int off = 4; off > 0; off >>= 1) {
                    c0 += __shfl_xor(c0, off);
                    c1 += __shfl_xor(c1, off);
                }
                if (fl == 0) {
                    fout[(size_t)node * 2 + 0] = c0 + cls_b[0];
                    fout[(size_t)node * 2 + 1] = c1 + cls_b[1];
                }
            }
            __syncthreads();
        }
    }
}

// ---------------- launch ----------------

extern "C" void kernel_launch(void* const* d_in, const int* in_sizes, int n_in,
                              void* d_out, int out_size, void* d_ws, size_t ws_size,
                              hipStream_t stream) {
    const float* x      = (const float*)d_in[0];
    const int*   ei     = (const int*)d_in[1];
    const float* w0     = (const float*)d_in[2];
    const float* w1     = (const float*)d_in[3];
    const float* w2     = (const float*)d_in[4];
    const float* biases = (const float*)d_in[5];
    const float* gamma  = (const float*)d_in[6];
    const float* beta   = (const float*)d_in[7];
    const float* rmean  = (const float*)d_in[8];
    const float* rvar   = (const float*)d_in[9];
    const float* cls_w  = (const float*)d_in[10];
    const float* cls_b  = (const float*)d_in[11];
    float* out = (float*)d_out;

    const int IN = 128, H = 64;
    const int N = in_sizes[0] / IN;   // 100000
    const int E = in_sizes[1] / 2;    // 1200000

    char* p = (char*)d_ws;
    auto carve = [&](size_t bytes) { void* q = (void*)p; p += (bytes + 255) & ~(size_t)255; return q; };
    float* dinv      = (float*)carve((size_t)N * 4);
    int* bucket_fill = (int*)carve((size_t)NBKT_MAX * 4);
    int* hb          = (int*)carve((size_t)NBKT_MAX * 4);
    unsigned* tmp    = (unsigned*)carve((size_t)NBKT_MAX * BCAP * 4);
    unsigned* eb     = (unsigned*)carve((size_t)NBKT_MAX * BCAP * 4);
    __half* tA       = (__half*)carve((size_t)N * H * 2);
    __half* tB       = (__half*)carve((size_t)N * H * 2);

    int nbuckets = (N + 255) >> 8;                    // 391
    int na = (E + ACHUNK - 1) / ACHUNK;               // 586

    hipMemsetAsync(bucket_fill, 0, (size_t)NBKT_MAX * 4, stream);
    bucketA_kernel<<<na, 256, 0, stream>>>(ei, E, bucket_fill, tmp);
    bucketB_kernel<<<nbuckets, 256, 0, stream>>>(tmp, bucket_fill, dinv, eb, hb, N);

    int gemm_grid = (N + 63) / 64;

    // layer 0 GEMM (x @ w0, dinv-scaled, fp16 out)
    gemm_kernel<128, float><<<gemm_grid, 256, 0, stream>>>(x, w0, dinv, tA, N);
    // layer 0 agg + BN/ReLU + layer-1 GEMM (push model)
    agg_push_kernel<false><<<nbuckets, 256, 0, stream>>>(tA, dinv, eb, bucket_fill, hb,
        biases + 0, gamma + 0, beta + 0, rmean + 0, rvar + 0, w1, nullptr, nullptr, tB, nullptr, N);
    // layer 1 agg + BN/ReLU + layer-2 GEMM
    agg_push_kernel<false><<<nbuckets, 256, 0, stream>>>(tB, dinv, eb, bucket_fill, hb,
        biases + H, gamma + H, beta + H, rmean + H, rvar + H, w2, nullptr, nullptr, tA, nullptr, N);
    // layer 2 agg + BN/ReLU + classifier
    agg_push_kernel<true><<<nbuckets, 256, 0, stream>>>(tA, dinv, eb, bucket_fill, hb,
        biases + 2 * H, gamma + 2 * H, beta + 2 * H, rmean + 2 * H, rvar + 2 * H,
        nullptr, cls_w, cls_b, nullptr, out, N);
}

// Round 8
// 237.355 us; speedup vs baseline: 7.2479x; 7.2479x over previous
//
#include <hip/hip_runtime.h>
#include <hip/hip_fp16.h>

#define EPS 1e-5f
#define ABITS 9           // 512 nodes per target-bucket
#define ACHUNK 4096       // edges per block in bucket pass A
#define BCAP 8192         // tmp capacity per bucket (avg ~6150, >26 sigma margin)
#define BCSR 12288        // padded csr capacity per bucket (<= BCAP + 512*7)
#define CSHIFT 13         // src-chunk = src >> 13 (1 MB of t per chunk)
#define NCHUNK 16
// tmp entry packing: (dstOff << 17) | src  — requires N <= 131072 (N=100000 ok)

typedef _Float16 half8 __attribute__((ext_vector_type(8)));
typedef float floatx4 __attribute__((ext_vector_type(4)));

// ---------------- graph prep (2 kernels, padded buckets, no global scan) ----------------

// A: single pass over ei — stage chunk in LDS, LDS histogram, reserve bucket runs,
// scatter packed entries from LDS (ei read once, 9.6 MB total).
__global__ __launch_bounds__(256) void bucketA_kernel(const int* __restrict__ ei, int E,
                                                      int* __restrict__ bucket_fill, unsigned* __restrict__ tmp) {
    __shared__ int2 edg[ACHUNK];            // 32 KB
    __shared__ int hist[256], lbase[256], lcur[256];
    int t = threadIdx.x;
    hist[t] = 0; lcur[t] = 0;
    __syncthreads();
    int e0 = blockIdx.x * ACHUNK;
    int e1 = e0 + ACHUNK; if (e1 > E) e1 = E;
    int ne = e1 - e0;
    for (int idx = t; idx < ne; idx += 256) {
        int r = ei[e0 + idx], c = ei[E + e0 + idx];
        edg[idx] = make_int2(r, c);
        atomicAdd(&hist[c >> ABITS], 1);
    }
    __syncthreads();
    int h = hist[t];
    if (h) lbase[t] = atomicAdd(&bucket_fill[t], h);
    __syncthreads();
    for (int idx = t; idx < ne; idx += 256) {
        int2 e = edg[idx];
        int b = e.y >> ABITS;
        int l = atomicAdd(&lcur[b], 1);
        tmp[(size_t)b * BCAP + lbase[b] + l] = ((unsigned)(e.y & 511) << 17) | (unsigned)e.x;
    }
}

// B: per bucket — stage packed edges in LDS, count (dst,chunk), scan PADDED counts,
// write rowse(start, start+deg) + dinv, place srcs grouped by src-chunk, then pad
// each node's list to a multiple of 8 with src=i (agg corrects with (1-k)*t[i]).
// Also histograms nodes by iteration-class k = ceil(deg/8) into classCnt (for perm).
__global__ __launch_bounds__(256) void bucketB_kernel(const unsigned* __restrict__ tmp,
                                                      const int* __restrict__ bucket_fill,
                                                      int2* __restrict__ rowse, float* __restrict__ dinv,
                                                      int* __restrict__ csr, int* __restrict__ classCnt, int n) {
    __shared__ unsigned edg[BCAP];          // 32 KB (packed)
    __shared__ int cnt2[512 * NCHUNK];      // 32 KB: counts -> seg cursors
    __shared__ int ps[256];
    __shared__ int ccnt[16];
    int b = blockIdx.x, t = threadIdx.x;
    int n0 = b << ABITS;
    int cntN = n - n0; if (cntN > 512) cntN = 512;
    int ne = bucket_fill[b]; if (ne > BCAP) ne = BCAP;
    int base = b * BCAP;
    int cbase = b * BCSR;
    if (t < 16) ccnt[t] = 0;
    for (int i = t; i < 512 * NCHUNK; i += 256) cnt2[i] = 0;
    for (int idx = t; idx < ne; idx += 256) edg[idx] = tmp[(size_t)base + idx];
    __syncthreads();
    for (int idx = t; idx < ne; idx += 256) {
        unsigned e = edg[idx];
        int dstOff = e >> 17, src = e & 0x1FFFF;
        atomicAdd(&cnt2[dstOff * NCHUNK + (src >> CSHIFT)], 1);
    }
    __syncthreads();
    int c0 = 0, c1 = 0;
#pragma unroll
    for (int c = 0; c < NCHUNK; ++c) {
        c0 += cnt2[(2 * t) * NCHUNK + c];
        c1 += cnt2[(2 * t + 1) * NCHUNK + c];
    }
    // degree-class histogram (iterations in agg = ceil(deg/8))
    {
        int k0c = (c0 + 7) >> 3; if (k0c > 15) k0c = 15;
        int k1c = (c1 + 7) >> 3; if (k1c > 15) k1c = 15;
        if (2 * t < cntN) atomicAdd(&ccnt[k0c], 1);
        if (2 * t + 1 < cntN) atomicAdd(&ccnt[k1c], 1);
    }
    int p0 = (c0 + 7) & ~7, p1 = (c1 + 7) & ~7;   // padded lengths
    int s = p0 + p1;
    ps[t] = s;
    __syncthreads();
    for (int off = 1; off < 256; off <<= 1) {
        int u = (t >= off) ? ps[t - off] : 0;
        __syncthreads();
        ps[t] += u;
        __syncthreads();
    }
    int excl = ps[t] - s;
    int st0 = cbase + excl, st1 = cbase + excl + p0;
    if (2 * t < cntN) {
        rowse[n0 + 2 * t] = make_int2(st0, st0 + c0);
        dinv[n0 + 2 * t] = rsqrtf((float)(c0 + 1));
    }
    if (2 * t + 1 < cntN) {
        rowse[n0 + 2 * t + 1] = make_int2(st1, st1 + c1);
        dinv[n0 + 2 * t + 1] = rsqrtf((float)(c1 + 1));
    }
    // pads: fill [start+deg, start+pdeg) with own node index (self row, L2-hot)
    if (2 * t < cntN)
        for (int j = c0; j < p0; ++j) csr[st0 + j] = n0 + 2 * t;
    if (2 * t + 1 < cntN)
        for (int j = c1; j < p1; ++j) csr[st1 + j] = n0 + 2 * t + 1;
    // counts -> per-(node,chunk) segment cursors
    int run = st0;
#pragma unroll
    for (int c = 0; c < NCHUNK; ++c) {
        int v = cnt2[(2 * t) * NCHUNK + c];
        cnt2[(2 * t) * NCHUNK + c] = run;
        run += v;
    }
    run = st1;
#pragma unroll
    for (int c = 0; c < NCHUNK; ++c) {
        int v = cnt2[(2 * t + 1) * NCHUNK + c];
        cnt2[(2 * t + 1) * NCHUNK + c] = run;
        run += v;
    }
    __syncthreads();
    for (int idx = t; idx < ne; idx += 256) {
        unsigned e = edg[idx];
        int dstOff = e >> 17, src = e & 0x1FFFF;
        int key = dstOff * NCHUNK + (src >> CSHIFT);
        int pos = atomicAdd(&cnt2[key], 1);
        csr[pos] = src;
    }
    __syncthreads();
    if (t < 16) atomicAdd(&classCnt[t], ccnt[t]);
}

// perm: stable-ish two-level counting sort of nodes by iteration-class.
// Groups of 8 consecutive perm-slots then share a degree class -> no wave divergence.
__global__ __launch_bounds__(256) void perm_kernel(const int2* __restrict__ rowse,
                                                   const int* __restrict__ classCnt,
                                                   int* __restrict__ classCur,
                                                   int* __restrict__ perm, int n) {
    __shared__ int lcnt[16], lbase[16], gbase[16];
    int t = threadIdx.x;
    if (t < 16) lcnt[t] = 0;
    __syncthreads();
    int i = blockIdx.x * 256 + t;
    int k = 0, lrank = 0;
    if (i < n) {
        int2 se = rowse[i];
        int deg = se.y - se.x;
        k = (deg + 7) >> 3; if (k > 15) k = 15;
        lrank = atomicAdd(&lcnt[k], 1);
    }
    __syncthreads();
    if (t < 16) {
        lbase[t] = atomicAdd(&classCur[t], lcnt[t]);
        int bsum = 0;
        for (int j = 0; j < t; ++j) bsum += classCnt[j];
        gbase[t] = bsum;
    }
    __syncthreads();
    if (i < n) perm[gbase[k] + lbase[k] + lrank] = i;
}

// ---------------- dense GEMM via MFMA: [n,K] @ [K,64] -> dinv[row] * result (f16) ----------------
// (used for layer 0 only; layers 1/2 GEMMs are fused into the agg epilogue)

template <int K, typename TIN>
__global__ __launch_bounds__(256) void gemm_kernel(const TIN* __restrict__ A, const float* __restrict__ W,
                                                   const float* __restrict__ dinv, __half* __restrict__ out, int n) {
    const int KP = K + 8;
    __shared__ _Float16 Ah[64 * (K + 8)];
    __shared__ _Float16 Wt[64 * (K + 8)];
    int tid = threadIdx.x;

    for (int idx = tid; idx < K * 64; idx += 256) {
        int k = idx >> 6, c = idx & 63;
        Wt[c * KP + k] = (_Float16)W[idx];
    }
    int row0 = blockIdx.x * 64;
    const TIN* Ab = A + (size_t)row0 * K;
    int limit = (n - row0) * K; if (limit > 64 * K) limit = 64 * K;

    if constexpr (sizeof(TIN) == 4) {   // float input
        for (int f = tid * 4; f < 64 * K; f += 1024) {
            float4 v = make_float4(0.f, 0.f, 0.f, 0.f);
            if (f + 3 < limit) {
                v = *(const float4*)((const float*)Ab + f);
            } else {
                if (f + 0 < limit) v.x = ((const float*)Ab)[f + 0];
                if (f + 1 < limit) v.y = ((const float*)Ab)[f + 1];
                if (f + 2 < limit) v.z = ((const float*)Ab)[f + 2];
            }
            int row = f / K, k = f % K;
            _Float16* dst = Ah + row * KP + k;
            dst[0] = (_Float16)v.x; dst[1] = (_Float16)v.y;
            dst[2] = (_Float16)v.z; dst[3] = (_Float16)v.w;
        }
    } else {                            // fp16 input: straight copy
        for (int f = tid * 8; f < 64 * K; f += 2048) {
            uint4 v = make_uint4(0, 0, 0, 0);
            if (f + 7 < limit) {
                v = *(const uint4*)((const __half*)Ab + f);
            } else {
                const __half* hp = (const __half*)Ab;
                __half tmp8[8];
                for (int j = 0; j < 8; ++j) tmp8[j] = (f + j < limit) ? hp[f + j] : __half(0);
                v = *(const uint4*)tmp8;
            }
            int row = f / K, k = f % K;
            *(uint4*)(Ah + row * KP + k) = v;
        }
    }
    __syncthreads();

    int w = tid >> 6, lane = tid & 63;
    int m = lane & 15, quad = lane >> 4;
    const _Float16* Aw = Ah + (size_t)(w * 16 + m) * KP + quad * 8;
    const _Float16* Bw = Wt + (size_t)m * KP + quad * 8;

    floatx4 acc0 = {0.f, 0.f, 0.f, 0.f}, acc1 = acc0, acc2 = acc0, acc3 = acc0;
    for (int k0 = 0; k0 < K; k0 += 32) {
        half8 a  = *(const half8*)(Aw + k0);
        half8 b0 = *(const half8*)(Bw + 0 * 16 * KP + k0);
        half8 b1 = *(const half8*)(Bw + 1 * 16 * KP + k0);
        half8 b2 = *(const half8*)(Bw + 2 * 16 * KP + k0);
        half8 b3 = *(const half8*)(Bw + 3 * 16 * KP + k0);
        acc0 = __builtin_amdgcn_mfma_f32_16x16x32_f16(a, b0, acc0, 0, 0, 0);
        acc1 = __builtin_amdgcn_mfma_f32_16x16x32_f16(a, b1, acc1, 0, 0, 0);
        acc2 = __builtin_amdgcn_mfma_f32_16x16x32_f16(a, b2, acc2, 0, 0, 0);
        acc3 = __builtin_amdgcn_mfma_f32_16x16x32_f16(a, b3, acc3, 0, 0, 0);
    }

    int rbase = row0 + w * 16 + quad * 4;
#pragma unroll
    for (int r = 0; r < 4; ++r) {
        int row = rbase + r;
        if (row < n) {
            float dv = dinv[row];
            __half* o = out + (size_t)row * 64 + m;
            o[0]  = __float2half(acc0[r] * dv);
            o[16] = __float2half(acc1[r] * dv);
            o[32] = __float2half(acc2[r] * dv);
            o[48] = __float2half(acc3[r] * dv);
        }
    }
}

// ---------------- aggregation + bias + BN(eval) + ReLU ----------------
// Full-row gather (8 lanes x 16 B = one 128 B line/edge). Wave = 8 independent
// 8-lane groups, one node per group. Nodes globally class-sorted via perm so
// the 8 groups of a wave run the same iteration count. Gather loop software-
// pipelined: next csr block prefetched before current gathers are consumed,
// breaking the serial csr->gather latency chain.

__device__ __forceinline__ void agg_add8(float4& lo, float4& hi, uint4 raw) {
    float2 p0 = __half22float2(*(const __half2*)&raw.x);
    float2 p1 = __half22float2(*(const __half2*)&raw.y);
    float2 p2 = __half22float2(*(const __half2*)&raw.z);
    float2 p3 = __half22float2(*(const __half2*)&raw.w);
    lo.x += p0.x; lo.y += p0.y; lo.z += p1.x; lo.w += p1.y;
    hi.x += p2.x; hi.y += p2.y; hi.z += p3.x; hi.w += p3.y;
}

// Core aggregation for one node i; returns BN/ReLU'd features in resL/resH and dinv in di.
__device__ __forceinline__ void agg_core(const __half* __restrict__ t, const float* __restrict__ dinv,
                                         const int2* __restrict__ rowse, const int* __restrict__ csr,
                                         const float* __restrict__ bias, const float* __restrict__ gamma,
                                         const float* __restrict__ beta, const float* __restrict__ mean,
                                         const float* __restrict__ var,
                                         int i, int fl, float4& resL, float4& resH, float& di) {
    int2 se = rowse[i];
    // self row (prefetch; also the pad-correction operand)
    uint4 self = *(const uint4*)(t + (size_t)i * 64 + fl * 8);

    float4 lo = make_float4(0.f, 0.f, 0.f, 0.f);
    float4 hi = make_float4(0.f, 0.f, 0.f, 0.f);

    int deg = se.y - se.x;
    int padEnd = se.x + ((deg + 7) & ~7);
    // pipelined gather: s0..s7 hold the csr block for the CURRENT iteration,
    // prefetched one iteration ahead.
    int s0, s1, s2, s3, s4, s5, s6, s7;
    {
        const int* cp = csr + se.x;
        s0 = cp[0]; s1 = cp[1]; s2 = cp[2]; s3 = cp[3];
        s4 = cp[4]; s5 = cp[5]; s6 = cp[6]; s7 = cp[7];
    }
    for (int e = se.x; e < padEnd; e += 8) {
        int t0 = s0, t1 = s1, t2 = s2, t3 = s3, t4 = s4, t5 = s5, t6 = s6, t7 = s7;
        if (e + 8 < padEnd) {
            const int* cp = csr + e + 8;
            s0 = cp[0]; s1 = cp[1]; s2 = cp[2]; s3 = cp[3];
            s4 = cp[4]; s5 = cp[5]; s6 = cp[6]; s7 = cp[7];
        }
        uint4 r0 = *(const uint4*)(t + (size_t)t0 * 64 + fl * 8);
        uint4 r1 = *(const uint4*)(t + (size_t)t1 * 64 + fl * 8);
        uint4 r2 = *(const uint4*)(t + (size_t)t2 * 64 + fl * 8);
        uint4 r3 = *(const uint4*)(t + (size_t)t3 * 64 + fl * 8);
        uint4 r4 = *(const uint4*)(t + (size_t)t4 * 64 + fl * 8);
        uint4 r5 = *(const uint4*)(t + (size_t)t5 * 64 + fl * 8);
        uint4 r6 = *(const uint4*)(t + (size_t)t6 * 64 + fl * 8);
        uint4 r7 = *(const uint4*)(t + (size_t)t7 * 64 + fl * 8);
        agg_add8(lo, hi, r0); agg_add8(lo, hi, r1); agg_add8(lo, hi, r2); agg_add8(lo, hi, r3);
        agg_add8(lo, hi, r4); agg_add8(lo, hi, r5); agg_add8(lo, hi, r6); agg_add8(lo, hi, r7);
    }

    // pad correction: padSum included k copies of t[i]; want edges + 1*t[i]
    float coef = 1.0f - (float)(padEnd - se.y);
    {
        float2 p0 = __half22float2(*(const __half2*)&self.x);
        float2 p1 = __half22float2(*(const __half2*)&self.y);
        float2 p2 = __half22float2(*(const __half2*)&self.z);
        float2 p3 = __half22float2(*(const __half2*)&self.w);
        lo.x += coef * p0.x; lo.y += coef * p0.y; lo.z += coef * p1.x; lo.w += coef * p1.y;
        hi.x += coef * p2.x; hi.y += coef * p2.y; hi.z += coef * p3.x; hi.w += coef * p3.y;
    }

    di = dinv[i];
    lo.x *= di; lo.y *= di; lo.z *= di; lo.w *= di;
    hi.x *= di; hi.y *= di; hi.z *= di; hi.w *= di;

    float4 bbL = ((const float4*)bias)[2 * fl],  bbH = ((const float4*)bias)[2 * fl + 1];
    float4 ggL = ((const float4*)gamma)[2 * fl], ggH = ((const float4*)gamma)[2 * fl + 1];
    float4 beL = ((const float4*)beta)[2 * fl],  beH = ((const float4*)beta)[2 * fl + 1];
    float4 mmL = ((const float4*)mean)[2 * fl],  mmH = ((const float4*)mean)[2 * fl + 1];
    float4 vvL = ((const float4*)var)[2 * fl],   vvH = ((const float4*)var)[2 * fl + 1];
    resL.x = fmaxf((lo.x + bbL.x - mmL.x) * (ggL.x * rsqrtf(vvL.x + EPS)) + beL.x, 0.f);
    resL.y = fmaxf((lo.y + bbL.y - mmL.y) * (ggL.y * rsqrtf(vvL.y + EPS)) + beL.y, 0.f);
    resL.z = fmaxf((lo.z + bbL.z - mmL.z) * (ggL.z * rsqrtf(vvL.z + EPS)) + beL.z, 0.f);
    resL.w = fmaxf((lo.w + bbL.w - mmL.w) * (ggL.w * rsqrtf(vvL.w + EPS)) + beL.w, 0.f);
    resH.x = fmaxf((hi.x + bbH.x - mmH.x) * (ggH.x * rsqrtf(vvH.x + EPS)) + beH.x, 0.f);
    resH.y = fmaxf((hi.y + bbH.y - mmH.y) * (ggH.y * rsqrtf(vvH.y + EPS)) + beH.y, 0.f);
    resH.z = fmaxf((hi.z + bbH.z - mmH.z) * (ggH.z * rsqrtf(vvH.z + EPS)) + beH.z, 0.f);
    resH.w = fmaxf((hi.w + bbH.w - mmH.w) * (ggH.w * rsqrtf(vvH.w + EPS)) + beH.w, 0.f);
}

// Fused: aggregation(+BN/ReLU) of 32 nodes -> LDS A-tile -> [32x64]@[64x64] MFMA
// -> dinv-scaled fp16 scatter-write of next layer's t rows.
// __launch_bounds__(256,6): 24 waves/CU (VGPR cap ~85 > ~65 needed) — latency hiding.
__global__ __launch_bounds__(256, 6) void agg_gemm_kernel(
        const __half* __restrict__ t, const float* __restrict__ dinv,
        const int2* __restrict__ rowse, const int* __restrict__ csr,
        const int* __restrict__ perm,
        const float* __restrict__ bias, const float* __restrict__ gamma,
        const float* __restrict__ beta, const float* __restrict__ mean,
        const float* __restrict__ var,
        const float* __restrict__ W,          // [64][64] row-major (k, c)
        __half* __restrict__ tout, int n) {
    const int KP = 72;
    __shared__ _Float16 Ah[32 * 72];          // 4.5 KB  (post-BN/ReLU h, fp16)
    __shared__ _Float16 Wt[64 * 72];          // 9 KB    (W transposed)
    __shared__ int   nidS[32];
    __shared__ float dvS[32];

    int tid = threadIdx.x;
    // stage W transposed (L2-broadcast-hot, 16 KB)
    for (int idx = tid; idx < 64 * 64; idx += 256) {
        int k = idx >> 6, c = idx & 63;
        Wt[c * KP + k] = (_Float16)W[idx];
    }

    int wave = tid >> 6, lane = tid & 63;
    int g = lane >> 3, fl = lane & 7;
    int slotInBlk = wave * 8 + g;
    int slot = blockIdx.x * 32 + slotInBlk;
    bool act = slot < n;

    if (act) {
        int i = perm[slot];
        float4 resL, resH; float di;
        agg_core(t, dinv, rowse, csr, bias, gamma, beta, mean, var, i, fl, resL, resH, di);
        __half2 h0 = __floats2half2_rn(resL.x, resL.y);
        __half2 h1 = __floats2half2_rn(resL.z, resL.w);
        __half2 h2 = __floats2half2_rn(resH.x, resH.y);
        __half2 h3 = __floats2half2_rn(resH.z, resH.w);
        uint4 pk;
        pk.x = *(unsigned*)&h0; pk.y = *(unsigned*)&h1;
        pk.z = *(unsigned*)&h2; pk.w = *(unsigned*)&h3;
        *(uint4*)(Ah + slotInBlk * KP + fl * 8) = pk;
        if (fl == 0) { nidS[slotInBlk] = i; dvS[slotInBlk] = di; }
    } else {
        uint4 z = make_uint4(0, 0, 0, 0);
        *(uint4*)(Ah + slotInBlk * KP + fl * 8) = z;
        if (fl == 0) { nidS[slotInBlk] = 0; dvS[slotInBlk] = 0.f; }
    }
    __syncthreads();

    // MFMA: wave w covers rows (w&1)*16..+15, cols (w>>1)*32..+31
    int m = lane & 15, quad = lane >> 4;
    int mrow = (wave & 1) * 16;
    int c0 = (wave >> 1) * 32;
    const _Float16* Aw = Ah + (mrow + m) * KP + quad * 8;
    const _Float16* Bw = Wt + (c0 + m) * KP + quad * 8;

    floatx4 acc0 = {0.f, 0.f, 0.f, 0.f}, acc1 = acc0;
#pragma unroll
    for (int k0 = 0; k0 < 64; k0 += 32) {
        half8 a  = *(const half8*)(Aw + k0);
        half8 b0 = *(const half8*)(Bw + k0);
        half8 b1 = *(const half8*)(Bw + 16 * KP + k0);
        acc0 = __builtin_amdgcn_mfma_f32_16x16x32_f16(a, b0, acc0, 0, 0, 0);
        acc1 = __builtin_amdgcn_mfma_f32_16x16x32_f16(a, b1, acc1, 0, 0, 0);
    }

#pragma unroll
    for (int r = 0; r < 4; ++r) {
        int row = mrow + quad * 4 + r;
        if (blockIdx.x * 32 + row < n) {
            int node = nidS[row];
            float dv = dvS[row];
            __half* o = tout + (size_t)node * 64;
            o[c0 + m]      = __float2half(acc0[r] * dv);
            o[c0 + 16 + m] = __float2half(acc1[r] * dv);
        }
    }
}

// Final layer: aggregation(+BN/ReLU) fused with the 64->2 classifier.
__global__ __launch_bounds__(256, 6) void agg_cls_kernel(
        const __half* __restrict__ t, const float* __restrict__ dinv,
        const int2* __restrict__ rowse, const int* __restrict__ csr,
        const int* __restrict__ perm,
        const float* __restrict__ bias, const float* __restrict__ gamma,
        const float* __restrict__ beta, const float* __restrict__ mean,
        const float* __restrict__ var,
        float* __restrict__ fout,
        const float* __restrict__ cls_w, const float* __restrict__ cls_b,
        int n) {
    int wave = threadIdx.x >> 6;
    int lane = threadIdx.x & 63;
    int g = lane >> 3;
    int fl = lane & 7;
    int slot = (blockIdx.x * (blockDim.x >> 6) + wave) * 8 + g;
    if (slot >= n) return;
    int i = perm[slot];

    float4 resL, resH; float di;
    agg_core(t, dinv, rowse, csr, bias, gamma, beta, mean, var, i, fl, resL, resH, di);

    const float4* cw = (const float4*)cls_w;
    float4 cwA = cw[4 * fl + 0], cwB = cw[4 * fl + 1], cwC = cw[4 * fl + 2], cwD = cw[4 * fl + 3];
    float c0 = resL.x * cwA.x + resL.y * cwA.z + resL.z * cwB.x + resL.w * cwB.z
             + resH.x * cwC.x + resH.y * cwC.z + resH.z * cwD.x + resH.w * cwD.z;
    float c1 = resL.x * cwA.y + resL.y * cwA.w + resL.z * cwB.y + resL.w * cwB.w
             + resH.x * cwC.y + resH.y * cwC.w + resH.z * cwD.y + resH.w * cwD.w;
    for (int off = 4; off > 0; off >>= 1) {
        c0 += __shfl_xor(c0, off);
        c1 += __shfl_xor(c1, off);
    }
    if (fl == 0) {
        fout[(size_t)i * 2 + 0] = c0 + cls_b[0];
        fout[(size_t)i * 2 + 1] = c1 + cls_b[1];
    }
}

// ---------------- launch ----------------

extern "C" void kernel_launch(void* const* d_in, const int* in_sizes, int n_in,
                              void* d_out, int out_size, void* d_ws, size_t ws_size,
                              hipStream_t stream) {
    const float* x      = (const float*)d_in[0];
    const int*   ei     = (const int*)d_in[1];
    const float* w0     = (const float*)d_in[2];
    const float* w1     = (const float*)d_in[3];
    const float* w2     = (const float*)d_in[4];
    const float* biases = (const float*)d_in[5];
    const float* gamma  = (const float*)d_in[6];
    const float* beta   = (const float*)d_in[7];
    const float* rmean  = (const float*)d_in[8];
    const float* rvar   = (const float*)d_in[9];
    const float* cls_w  = (const float*)d_in[10];
    const float* cls_b  = (const float*)d_in[11];
    float* out = (float*)d_out;

    const int IN = 128, H = 64;
    const int N = in_sizes[0] / IN;   // 100000
    const int E = in_sizes[1] / 2;    // 1200000

    char* p = (char*)d_ws;
    auto carve = [&](size_t bytes) { void* q = (void*)p; p += (bytes + 255) & ~(size_t)255; return q; };
    float* dinv    = (float*)carve((size_t)N * 4);
    int2*  rowse   = (int2*)carve((size_t)N * 8);
    int*   meta    = (int*)carve((size_t)288 * 4);   // bucket_fill[256] | classCnt[16] | classCur[16]
    int*   perm    = (int*)carve((size_t)N * 4);
    unsigned* tmp  = (unsigned*)carve((size_t)256 * BCAP * 4);
    int*   csr     = (int*)carve((size_t)256 * BCSR * 4);
    __half* tA     = (__half*)carve((size_t)N * H * 2);
    __half* tB     = (__half*)carve((size_t)N * H * 2);

    int* bucket_fill = meta;
    int* classCnt    = meta + 256;
    int* classCur    = meta + 272;

    int nbuckets = (N + (1 << ABITS) - 1) >> ABITS;   // 196 for N=100000
    int na = (E + ACHUNK - 1) / ACHUNK;               // 293

    hipMemsetAsync(meta, 0, (size_t)288 * 4, stream);
    bucketA_kernel<<<na, 256, 0, stream>>>(ei, E, bucket_fill, tmp);
    bucketB_kernel<<<nbuckets, 256, 0, stream>>>(tmp, bucket_fill, rowse, dinv, csr, classCnt, N);
    perm_kernel<<<(N + 255) / 256, 256, 0, stream>>>(rowse, classCnt, classCur, perm, N);

    int gemm_grid = (N + 63) / 64;
    int agg_grid  = (N + 31) / 32;   // 32 nodes per block (4 waves x 8 groups)

    // layer 0
    gemm_kernel<128, float><<<gemm_grid, 256, 0, stream>>>(x, w0, dinv, tA, N);
    agg_gemm_kernel<<<agg_grid, 256, 0, stream>>>(tA, dinv, rowse, csr, perm,
        biases + 0, gamma + 0, beta + 0, rmean + 0, rvar + 0, w1, tB, N);
    agg_gemm_kernel<<<agg_grid, 256, 0, stream>>>(tB, dinv, rowse, csr, perm,
        biases + H, gamma + H, beta + H, rmean + H, rvar + H, w2, tA, N);
    agg_cls_kernel<<<agg_grid, 256, 0, stream>>>(tA, dinv, rowse, csr, perm,
        biases + 2 * H, gamma + 2 * H, beta + 2 * H, rmean + 2 * H, rvar + 2 * H,
        out, cls_w, cls_b, N);
}